// Round 1
// baseline (1250.421 us; speedup 1.0000x reference)
//
#include <hip/hip_runtime.h>
#include <hip/hip_bf16.h>
#include <math.h>

#define DM 768
#define DI 1536
#define DSN 16
#define NB 2
#define SL 1024
#define MROWS 2048
#define VOC 50257
#define VOCP 50304
#define EPSR 1e-5f

typedef __attribute__((ext_vector_type(8))) short short8;
typedef __attribute__((ext_vector_type(4))) float f32x4;
typedef unsigned short u16;

__device__ inline u16 f2bf(float f) {
    unsigned u = __builtin_bit_cast(unsigned, f);
    u += 0x7FFFu + ((u >> 16) & 1u);   // round-to-nearest-even
    return (u16)(u >> 16);
}

// ---------------- embedding gather ----------------
__global__ void k_embed(const int* __restrict__ tok, const float* __restrict__ emb,
                        float* __restrict__ x) {
    int r = blockIdx.x;
    int t = tok[r];
    const float* src = emb + (size_t)t * DM;
    float* dst = x + (size_t)r * DM;
    for (int i = threadIdx.x; i < DM; i += 256) dst[i] = src[i];
}

// ---------------- RMSNorm -> bf16 ----------------
__global__ __launch_bounds__(256)
void k_rmsnorm_bf16(const float* __restrict__ x, const float* __restrict__ w,
                    u16* __restrict__ out) {
    int r = blockIdx.x;
    const float* row = x + (size_t)r * DM;
    int c0 = threadIdx.x * 3;
    float v[3]; float ss = 0.f;
#pragma unroll
    for (int i = 0; i < 3; ++i) { v[i] = row[c0 + i]; ss += v[i] * v[i]; }
#pragma unroll
    for (int o = 32; o > 0; o >>= 1) ss += __shfl_down(ss, o);
    __shared__ float s[4];
    int lane = threadIdx.x & 63, wv = threadIdx.x >> 6;
    if (lane == 0) s[wv] = ss;
    __syncthreads();
    float sc = rsqrtf((s[0] + s[1] + s[2] + s[3]) / (float)DM + EPSR);
#pragma unroll
    for (int i = 0; i < 3; ++i)
        out[(size_t)r * DM + c0 + i] = f2bf(v[i] * sc * w[c0 + i]);
}

// ---------------- f32 -> bf16 with 2D pad (rows/cols), src leading dim sld ----------------
__global__ void k_cvt_pad(const float* __restrict__ src, u16* __restrict__ dst,
                          int sr, int sc, int sld, int dc, long total) {
    long i = (long)blockIdx.x * 256 + threadIdx.x;
    if (i >= total) return;
    int r = (int)(i / dc), c = (int)(i % dc);
    float v = (r < sr && c < sc) ? src[(size_t)r * sld + c] : 0.f;
    dst[i] = f2bf(v);
}

// ---------------- causal depthwise conv (width 4) + bias + silu ----------------
__global__ void k_conv_silu(const float* __restrict__ xz, const float* __restrict__ cw,
                            const float* __restrict__ cb, float* __restrict__ uc,
                            u16* __restrict__ ucb) {
    int d = blockIdx.x * 256 + threadIdx.x;   // 0..1535
    int r = blockIdx.y;                       // 0..2047
    int l = r & (SL - 1);
    float acc = cb[d];
#pragma unroll
    for (int j = 0; j < 4; ++j) {
        int ls = l - 3 + j;
        if (ls >= 0) acc += xz[(size_t)(r - 3 + j) * (2 * DI) + d] * cw[d * 4 + j];
    }
    float s = acc / (1.f + __expf(-acc));
    uc[(size_t)r * DI + d] = s;
    ucb[(size_t)r * DI + d] = f2bf(s);
}

// ---------------- softplus(dt + b) ----------------
__global__ void k_softplus(const float* __restrict__ in, const float* __restrict__ b,
                           float* __restrict__ out) {
    int i = blockIdx.x * 256 + threadIdx.x;   // 2048*1536
    int d = i % DI;
    float v = in[i] + b[d];
    out[i] = (v > 20.f) ? v : log1pf(__expf(v));
}

// ---------------- selective scan + D-skip + silu(z) gate -> bf16 ----------------
__global__ __launch_bounds__(256)
void k_scan(const float* __restrict__ delta, const float* __restrict__ uc,
            const float* __restrict__ xdbl, const float* __restrict__ xz,
            const float* __restrict__ alog, const float* __restrict__ Dp,
            u16* __restrict__ ybf) {
    int b  = blockIdx.x / 96;
    int d0 = (blockIdx.x % 96) * 16;
    int tid = threadIdx.x, n = tid & 15, ch = tid >> 4;
    int d = d0 + ch;
    float A  = -__expf(alog[d * DSN + n]);
    float Dv = Dp[d];
    __shared__ float ds_[32][16], us_[32][16], bs_[32][16], cs_[32][16], zs_[32][16];
    float h = 0.f;
    for (int t0 = 0; t0 < SL; t0 += 32) {
        __syncthreads();
#pragma unroll
        for (int e = 0; e < 2; ++e) {
            int lin = e * 256 + tid; int tt = lin >> 4; int cc = lin & 15;
            size_t row = (size_t)(b * SL + t0 + tt);
            ds_[tt][cc] = delta[row * DI + d0 + cc];
            us_[tt][cc] = uc[row * DI + d0 + cc];
            zs_[tt][cc] = xz[row * (2 * DI) + DI + d0 + cc];
            bs_[tt][cc] = xdbl[row * 128 + 48 + cc];
            cs_[tt][cc] = xdbl[row * 128 + 64 + cc];
        }
        __syncthreads();
        for (int tt = 0; tt < 32; ++tt) {
            float dl = ds_[tt][ch];
            float uv = us_[tt][ch];
            float dA = __expf(dl * A);
            h = h * dA + dl * bs_[tt][n] * uv;
            float p = h * cs_[tt][n];
            p += __shfl_xor(p, 1);
            p += __shfl_xor(p, 2);
            p += __shfl_xor(p, 4);
            p += __shfl_xor(p, 8);
            if (n == 0) {
                float y = p + uv * Dv;
                float z = zs_[tt][ch];
                y *= z / (1.f + __expf(-z));
                ybf[(size_t)(b * SL + t0 + tt) * DI + d] = f2bf(y);
            }
        }
    }
}

// ---------------- bf16 MFMA GEMM: C[M,N](f32) = A[M,K](bf16) @ W[N,K]^T(bf16) ----------------
// 128x128 tile, BK=32, 4 waves (2x2 of 64x64), global_load_lds width-16 staging.
template <bool ADD_RES, bool NGUARD>
__global__ __launch_bounds__(256)
void k_gemm_bt(const u16* __restrict__ A, const u16* __restrict__ W,
               float* __restrict__ C, const float* __restrict__ RES,
               int K, int ldc, int nmax) {
    __shared__ u16 Al[128 * 32];
    __shared__ u16 Wl[128 * 32];
    int m0 = blockIdx.y * 128, n0 = blockIdx.x * 128;
    int tid = threadIdx.x, wave = tid >> 6, lane = tid & 63;
    int wm = wave >> 1, wn = wave & 1;
    f32x4 acc[4][4] = {};
    const int rS = (lane >> 2);            // staging row within 16-row chunk
    const int kS = (lane & 3) * 8;         // staging k offset (elements)
    const int kofs = (lane >> 4) * 8;      // fragment k offset
    const int fr = lane & 15;              // fragment row/col

    for (int k0 = 0; k0 < K; k0 += 32) {
#pragma unroll
        for (int i = 0; i < 2; ++i) {
            int rowA = m0 + wave * 32 + i * 16 + rS;
            const u16* ga = A + (size_t)rowA * K + k0 + kS;
            __builtin_amdgcn_global_load_lds(
                (const __attribute__((address_space(1))) void*)ga,
                (__attribute__((address_space(3))) void*)(&Al[wave * 1024 + i * 512]),
                16, 0, 0);
            int rowW = n0 + wave * 32 + i * 16 + rS;
            const u16* gw = W + (size_t)rowW * K + k0 + kS;
            __builtin_amdgcn_global_load_lds(
                (const __attribute__((address_space(1))) void*)gw,
                (__attribute__((address_space(3))) void*)(&Wl[wave * 1024 + i * 512]),
                16, 0, 0);
        }
        __syncthreads();
        short8 af[4], bfr[4];
#pragma unroll
        for (int f = 0; f < 4; ++f) {
            af[f]  = *(const short8*)&Al[(wm * 64 + f * 16 + fr) * 32 + kofs];
            bfr[f] = *(const short8*)&Wl[(wn * 64 + f * 16 + fr) * 32 + kofs];
        }
#pragma unroll
        for (int i = 0; i < 4; ++i)
#pragma unroll
            for (int j = 0; j < 4; ++j)
                acc[i][j] = __builtin_amdgcn_mfma_f32_16x16x32_bf16(af[i], bfr[j], acc[i][j], 0, 0, 0);
        __syncthreads();
    }
    int r4 = (lane >> 4) * 4;
#pragma unroll
    for (int i = 0; i < 4; ++i)
#pragma unroll
        for (int j = 0; j < 4; ++j)
#pragma unroll
            for (int rr = 0; rr < 4; ++rr) {
                int row = m0 + wm * 64 + i * 16 + r4 + rr;
                int col = n0 + wn * 64 + j * 16 + fr;
                if (!NGUARD || col < nmax) {
                    size_t off = (size_t)row * ldc + col;
                    float v = acc[i][j][rr];
                    if (ADD_RES) v += RES[off];
                    C[off] = v;
                }
            }
}

// ---------------- host ----------------
extern "C" void kernel_launch(void* const* d_in, const int* in_sizes, int n_in,
                              void* d_out, int out_size, void* d_ws, size_t ws_size,
                              hipStream_t stream) {
    (void)in_sizes; (void)n_in; (void)out_size;
    const int*   tok   = (const int*)d_in[0];
    const float* emb   = (const float*)d_in[1];
    const float* normw = (const float*)d_in[2];
    const float* inw   = (const float*)d_in[3];
    const float* cw    = (const float*)d_in[4];
    const float* cb    = (const float*)d_in[5];
    const float* xpw   = (const float*)d_in[6];
    const float* dtw   = (const float*)d_in[7];
    const float* dtb   = (const float*)d_in[8];
    const float* alog  = (const float*)d_in[9];
    const float* Dp    = (const float*)d_in[10];
    const float* outw  = (const float*)d_in[11];
    const float* normf = (const float*)d_in[12];
    const float* lmw   = (const float*)d_in[13];
    float* out = (float*)d_out;

    char* p = (char*)d_ws;
    auto alloc = [&](size_t bytes) { char* r = p; p += (bytes + 255) & ~(size_t)255; return r; };
    float* x     = (float*)alloc((size_t)MROWS * DM * 4);
    u16*   xnb   = (u16*)  alloc((size_t)MROWS * DM * 2);
    float* xz    = (float*)alloc((size_t)MROWS * 2 * DI * 4);
    float* uc    = (float*)alloc((size_t)MROWS * DI * 4);
    u16*   ucb   = (u16*)  alloc((size_t)MROWS * DI * 2);
    float* xdbl  = (float*)alloc((size_t)MROWS * 128 * 4);
    u16*   xdblb = (u16*)  alloc((size_t)MROWS * 64 * 2);
    float* dtraw = (float*)alloc((size_t)MROWS * DI * 4);
    float* delta = (float*)alloc((size_t)MROWS * DI * 4);
    u16*   ybf   = (u16*)  alloc((size_t)MROWS * DI * 2);
    u16*   winb  = (u16*)  alloc((size_t)(2 * DI) * DM * 2);
    u16*   wxpb  = (u16*)  alloc((size_t)128 * DI * 2);
    u16*   wdtb  = (u16*)  alloc((size_t)DI * 64 * 2);
    u16*   woutb = (u16*)  alloc((size_t)DM * DI * 2);
    u16*   wlmb  = (u16*)  alloc((size_t)VOCP * DM * 2);
    if ((size_t)(p - (char*)d_ws) > ws_size) return;  // insufficient scratch: fail loudly

    // lm_head weight -> bf16, padded to 50304 rows
    {
        long tot = (long)VOCP * DM;
        k_cvt_pad<<<dim3((unsigned)((tot + 255) / 256)), 256, 0, stream>>>(
            lmw, wlmb, VOC, DM, DM, DM, tot);
    }

    k_embed<<<MROWS, 256, 0, stream>>>(tok, emb, x);

    for (int i = 0; i < NB; ++i) {
        k_rmsnorm_bf16<<<MROWS, 256, 0, stream>>>(x, normw + i * DM, xnb);

        { long tot = (long)(2 * DI) * DM;
          k_cvt_pad<<<dim3((unsigned)((tot + 255) / 256)), 256, 0, stream>>>(
              inw + (size_t)i * 2 * DI * DM, winb, 2 * DI, DM, DM, DM, tot); }
        k_gemm_bt<false, false><<<dim3(2 * DI / 128, MROWS / 128), 256, 0, stream>>>(
            xnb, winb, xz, nullptr, DM, 2 * DI, 2 * DI);

        k_conv_silu<<<dim3(DI / 256, MROWS), 256, 0, stream>>>(
            xz, cw + (size_t)i * DI * 4, cb + (size_t)i * DI, uc, ucb);

        { long tot = (long)128 * DI;
          k_cvt_pad<<<dim3((unsigned)((tot + 255) / 256)), 256, 0, stream>>>(
              xpw + (size_t)i * 80 * DI, wxpb, 80, DI, DI, DI, tot); }
        k_gemm_bt<false, false><<<dim3(1, MROWS / 128), 256, 0, stream>>>(
            ucb, wxpb, xdbl, nullptr, DI, 128, 128);

        { long tot = (long)MROWS * 64;
          k_cvt_pad<<<dim3((unsigned)((tot + 255) / 256)), 256, 0, stream>>>(
              xdbl, xdblb, MROWS, 64, 128, 64, tot); }
        { long tot = (long)DI * 64;
          k_cvt_pad<<<dim3((unsigned)((tot + 255) / 256)), 256, 0, stream>>>(
              dtw + (size_t)i * DI * 48, wdtb, DI, 48, 48, 64, tot); }
        k_gemm_bt<false, false><<<dim3(DI / 128, MROWS / 128), 256, 0, stream>>>(
            xdblb, wdtb, dtraw, nullptr, 64, DI, DI);

        k_softplus<<<dim3(MROWS * DI / 256), 256, 0, stream>>>(dtraw, dtb + i * DI, delta);

        k_scan<<<dim3(NB * (DI / 16)), 256, 0, stream>>>(
            delta, uc, xdbl, xz, alog + (size_t)i * DI * DSN, Dp + i * DI, ybf);

        { long tot = (long)DM * DI;
          k_cvt_pad<<<dim3((unsigned)((tot + 255) / 256)), 256, 0, stream>>>(
              outw + (size_t)i * DM * DI, woutb, DM, DI, DI, DI, tot); }
        k_gemm_bt<true, false><<<dim3(DM / 128, MROWS / 128), 256, 0, stream>>>(
            ybf, woutb, x, x, DI, DM, DM);
    }

    k_rmsnorm_bf16<<<MROWS, 256, 0, stream>>>(x, normf, xnb);
    k_gemm_bt<false, true><<<dim3(VOCP / 128, MROWS / 128), 256, 0, stream>>>(
        xnb, wlmb, out, nullptr, DM, VOC, VOC);
}